// Round 2
// baseline (91.339 us; speedup 1.0000x reference)
//
#include <hip/hip_runtime.h>

#define DIM 512
#define TEMP 0.5f
#define EPS 1e-8f
#define BT 512            // threads per block = 8 waves
#define ROWS_PER_BLK 64   // 8 rows per wave, fully unrolled
#define PSTRIDE (DIM + 1) // per-block partial: 512 s-elements + 1 diag

// Phase 1: each block reduces 64 rows -> one partial s-vector (512 floats) + diag sum.
// One wave per row-slice; lane l holds elements [4l,4l+4) and [256+4l,...) via two
// coalesced float4 loads. No atomics: partials land in ws[block*513 ...].
__global__ __launch_bounds__(BT) void accum_kernel(const float* __restrict__ x,
                                                   float* __restrict__ part, int N) {
    const int tid  = threadIdx.x;
    const int wave = tid >> 6;
    const int lane = tid & 63;
    const int rowBase = blockIdx.x * ROWS_PER_BLK;

    float4 accA = make_float4(0.f, 0.f, 0.f, 0.f);
    float4 accB = make_float4(0.f, 0.f, 0.f, 0.f);
    float diag = 0.f;

    if (rowBase + ROWS_PER_BLK <= N) {
        #pragma unroll
        for (int rr = 0; rr < 8; ++rr) {
            const int row = rowBase + wave + rr * 8;
            const float4* p = (const float4*)(x + (size_t)row * DIM);
            const float4 a = p[lane];
            const float4 b = p[lane + 64];
            float ss = a.x * a.x + a.y * a.y + a.z * a.z + a.w * a.w
                     + b.x * b.x + b.y * b.y + b.z * b.z + b.w * b.w;
            #pragma unroll
            for (int off = 1; off < 64; off <<= 1) ss += __shfl_xor(ss, off);
            const float inv = 1.0f / fmaxf(sqrtf(ss), EPS);
            if (lane == 0) diag += ss * inv * inv;
            accA.x = fmaf(a.x, inv, accA.x); accA.y = fmaf(a.y, inv, accA.y);
            accA.z = fmaf(a.z, inv, accA.z); accA.w = fmaf(a.w, inv, accA.w);
            accB.x = fmaf(b.x, inv, accB.x); accB.y = fmaf(b.y, inv, accB.y);
            accB.z = fmaf(b.z, inv, accB.z); accB.w = fmaf(b.w, inv, accB.w);
        }
    } else {
        for (int rr = 0; rr < 8; ++rr) {
            const int row = rowBase + wave + rr * 8;
            if (row >= N) break;
            const float4* p = (const float4*)(x + (size_t)row * DIM);
            const float4 a = p[lane];
            const float4 b = p[lane + 64];
            float ss = a.x * a.x + a.y * a.y + a.z * a.z + a.w * a.w
                     + b.x * b.x + b.y * b.y + b.z * b.z + b.w * b.w;
            #pragma unroll
            for (int off = 1; off < 64; off <<= 1) ss += __shfl_xor(ss, off);
            const float inv = 1.0f / fmaxf(sqrtf(ss), EPS);
            if (lane == 0) diag += ss * inv * inv;
            accA.x = fmaf(a.x, inv, accA.x); accA.y = fmaf(a.y, inv, accA.y);
            accA.z = fmaf(a.z, inv, accA.z); accA.w = fmaf(a.w, inv, accA.w);
            accB.x = fmaf(b.x, inv, accB.x); accB.y = fmaf(b.y, inv, accB.y);
            accB.z = fmaf(b.z, inv, accB.z); accB.w = fmaf(b.w, inv, accB.w);
        }
    }

    // Combine the 8 waves' partials in LDS (b128 writes: conflict-free pattern).
    __shared__ float sred[8][DIM];
    __shared__ float dred[8];
    *(float4*)&sred[wave][lane * 4]       = accA;
    *(float4*)&sred[wave][256 + lane * 4] = accB;
    if (lane == 0) dred[wave] = diag;
    __syncthreads();

    // tid in [0,512) == one s-element each; stride-1 reads, conflict-free.
    float v = 0.f;
    #pragma unroll
    for (int w = 0; w < 8; ++w) v += sred[w][tid];
    part[(size_t)blockIdx.x * PSTRIDE + tid] = v;
    if (tid == 0) {
        float d = 0.f;
        #pragma unroll
        for (int w = 0; w < 8; ++w) d += dred[w];
        part[(size_t)blockIdx.x * PSTRIDE + DIM] = d;
    }
}

// Phase 2: one block folds nblk partial vectors -> scalar.
__global__ __launch_bounds__(BT) void finalize_kernel(const float* __restrict__ part,
                                                      float* __restrict__ out,
                                                      int nblk, int N) {
    const int t = threadIdx.x;
    float acc = 0.f;
    #pragma unroll 8
    for (int b = 0; b < nblk; ++b) acc += part[(size_t)b * PSTRIDE + t];
    float v = acc * acc;                                   // contributes to ||s||^2
    if (t < nblk) v -= part[(size_t)t * PSTRIDE + DIM];    // subtract diag partials
    #pragma unroll
    for (int off = 1; off < 64; off <<= 1) v += __shfl_xor(v, off);

    __shared__ float wred[8];
    if ((t & 63) == 0) wred[t >> 6] = v;
    __syncthreads();
    if (t == 0) {
        float tot = 0.f;
        #pragma unroll
        for (int w = 0; w < 8; ++w) tot += wred[w];
        out[0] = tot / (TEMP * (float)N);
    }
}

extern "C" void kernel_launch(void* const* d_in, const int* in_sizes, int n_in,
                              void* d_out, int out_size, void* d_ws, size_t ws_size,
                              hipStream_t stream) {
    const float* x = (const float*)d_in[0];
    float* part = (float*)d_ws;
    float* out = (float*)d_out;
    const int N = in_sizes[0] / DIM;               // 16384
    const int nblk = (N + ROWS_PER_BLK - 1) / ROWS_PER_BLK;  // 256

    accum_kernel<<<nblk, BT, 0, stream>>>(x, part, N);
    finalize_kernel<<<1, BT, 0, stream>>>(part, out, nblk, N);
}